// Round 11
// baseline (494.497 us; speedup 1.0000x reference)
//
#include <hip/hip_runtime.h>
#include <hip/hip_bf16.h>
#include <stdint.h>

#define N_NODES   100000
#define N_EDGES   3200000
#define IN_FEAT   128
#define OUT_FEAT  128
#define NUM_RELS  16
#define NUM_BASES 8
#define M_PAD     100096      // 782 * 128
#define NBKT      391         // coarse buckets = ceil(100000/256)
#define NB        512         // blocks in coarse hist/place (must match both)
#define ZROW      1032        // padded bf16 per LDS z row (2064 B) -> 2-way banks

using short8 = __attribute__((ext_vector_type(8))) short;
using v4f    = __attribute__((ext_vector_type(4))) float;

__device__ inline unsigned short f2bf_rne(float f) {
    __hip_bfloat16 h = __float2bfloat16(f);
    return *reinterpret_cast<unsigned short*>(&h);
}
__device__ inline float bf2f(unsigned short u) {
    union { uint32_t i; float f; } x;
    x.i = ((uint32_t)u) << 16;
    return x.f;
}

// ---------------------------------------------------------------------------
// x fp32 -> bf16, zero-padded to M_PAD rows
// ---------------------------------------------------------------------------
__global__ void conv_x(const float* __restrict__ x, unsigned short* __restrict__ xb) {
    int id = blockIdx.x * 256 + threadIdx.x;
    int base = id * 4;
    ushort4 o;
    if (base < N_NODES * IN_FEAT) {
        const float4 v = reinterpret_cast<const float4*>(x)[id];
        o.x = f2bf_rne(v.x); o.y = f2bf_rne(v.y);
        o.z = f2bf_rne(v.z); o.w = f2bf_rne(v.w);
    } else {
        o.x = o.y = o.z = o.w = 0;
    }
    reinterpret_cast<ushort4*>(xb)[id] = o;
}

// ---------------------------------------------------------------------------
// Ut[o][b*128+i] = bf16(weight[b][i][o]) -- basis matrices, transposed.
// 128 x 1024 bf16 = 256 KB (L2-resident during the fused kernel).
// ---------------------------------------------------------------------------
__global__ void build_ut(const float* __restrict__ weight,
                         unsigned short* __restrict__ Ut) {
    int id = blockIdx.x * 256 + threadIdx.x;   // 512 blocks * 256 = 131072
    int o  = id >> 10;
    int kk = id & 1023;
    int b  = kk >> 7;
    int i  = kk & 127;
    Ut[id] = f2bf_rne(weight[(b * IN_FEAT + i) * OUT_FEAT + o]);
}

// ---------------------------------------------------------------------------
// Sort by dst. Coarse bucket b = dst>>8.
// Phase 1: per-block LDS histogram -> histG[b*NB + nb]  (no global atomics)
// ---------------------------------------------------------------------------
__global__ __launch_bounds__(512) void coarse_hist(const int* __restrict__ dst,
                                                   int* __restrict__ histG,
                                                   int nbuck) {
    extern __shared__ int lh[];
    for (int i = threadIdx.x; i < nbuck; i += 512) lh[i] = 0;
    __syncthreads();
    const int NG = N_EDGES / 4;
    const int stride = NB * 512;
    for (int g = blockIdx.x * 512 + threadIdx.x; g < NG; g += stride) {
        const int4 d4 = reinterpret_cast<const int4*>(dst)[g];
        atomicAdd(&lh[d4.x >> 8], 1);
        atomicAdd(&lh[d4.y >> 8], 1);
        atomicAdd(&lh[d4.z >> 8], 1);
        atomicAdd(&lh[d4.w >> 8], 1);
    }
    __syncthreads();
    for (int i = threadIdx.x; i < nbuck; i += 512)
        histG[i * NB + blockIdx.x] = lh[i];
}

// ---------------------------------------------------------------------------
// 2-level in-place exclusive scan of data[0..K): part -> mid -> final
// ---------------------------------------------------------------------------
__global__ void scan_part(const int* __restrict__ data, int* __restrict__ partial, int K) {
    __shared__ int sh[256];
    const int tid = threadIdx.x, b = blockIdx.x;
    const int i0 = b * 4096 + tid * 16;
    int s = 0;
#pragma unroll
    for (int k = 0; k < 16; ++k) { int i = i0 + k; if (i < K) s += data[i]; }
    sh[tid] = s;
    __syncthreads();
    for (int st = 128; st > 0; st >>= 1) {
        if (tid < st) sh[tid] += sh[tid + st];
        __syncthreads();
    }
    if (tid == 0) partial[b] = sh[0];
}

__global__ __launch_bounds__(512) void scan_mid(int* __restrict__ partial, int G) {
    __shared__ int sh[512];
    const int tid = threadIdx.x;
    int v = (tid < G) ? partial[tid] : 0;
    sh[tid] = v;
    __syncthreads();
    for (int st = 1; st < 512; st <<= 1) {
        int t = (tid >= st) ? sh[tid - st] : 0;
        __syncthreads();
        sh[tid] += t;
        __syncthreads();
    }
    if (tid < G) partial[tid] = sh[tid] - v;        // exclusive
}

// in-place: each element read before overwrite by the same thread
__global__ void scan_final(int* __restrict__ data, const int* __restrict__ partial, int K) {
    __shared__ int sh[256];
    const int tid = threadIdx.x, b = blockIdx.x;
    const int i0 = b * 4096 + tid * 16;
    int s = 0;
#pragma unroll
    for (int k = 0; k < 16; ++k) { int i = i0 + k; if (i < K) s += data[i]; }
    sh[tid] = s;
    __syncthreads();
    for (int st = 1; st < 256; st <<= 1) {
        int t = (tid >= st) ? sh[tid - st] : 0;
        __syncthreads();
        sh[tid] += t;
        __syncthreads();
    }
    int run = partial[b] + sh[tid] - s;
#pragma unroll
    for (int k = 0; k < 16; ++k) {
        int i = i0 + k;
        if (i < K) {
            int c = data[i];
            data[i] = run;
            run += c;
        }
    }
}

// ---------------------------------------------------------------------------
// Phase 2: place edges into bucket-contiguous regions using exact reserved
// ranges (histS = scanned histG). LDS cursors only.
// entry = (dst&255)<<21 | rl<<17 | src   (29 bits; src < 2^17)
// ---------------------------------------------------------------------------
__global__ __launch_bounds__(512) void coarse_place(const int* __restrict__ src,
                                                    const int* __restrict__ dst,
                                                    const int* __restrict__ et,
                                                    const int* __restrict__ histS,
                                                    int* __restrict__ entries,
                                                    int nbuck) {
    extern __shared__ int cur[];
    for (int i = threadIdx.x; i < nbuck; i += 512)
        cur[i] = histS[i * NB + blockIdx.x];
    __syncthreads();
    const int NG = N_EDGES / 4;
    const int stride = NB * 512;
    for (int g = blockIdx.x * 512 + threadIdx.x; g < NG; g += stride) {
        const int4 s4 = reinterpret_cast<const int4*>(src)[g];
        const int4 d4 = reinterpret_cast<const int4*>(dst)[g];
        const int4 t4 = reinterpret_cast<const int4*>(et)[g];
        int p0 = atomicAdd(&cur[d4.x >> 8], 1);
        int p1 = atomicAdd(&cur[d4.y >> 8], 1);
        int p2 = atomicAdd(&cur[d4.z >> 8], 1);
        int p3 = atomicAdd(&cur[d4.w >> 8], 1);
        entries[p0] = ((d4.x & 255) << 21) | ((t4.x & 15) << 17) | s4.x;
        entries[p1] = ((d4.y & 255) << 21) | ((t4.y & 15) << 17) | s4.y;
        entries[p2] = ((d4.z & 255) << 21) | ((t4.z & 15) << 17) | s4.z;
        entries[p3] = ((d4.w & 255) << 21) | ((t4.w & 15) << 17) | s4.w;
    }
}

// ---------------------------------------------------------------------------
// Phase 3: one block per bucket; counting sort by 12-bit key (dlow<<4 | rl)
// in LDS (2-pass). Edge lists become rel-contiguous per node, enabling the
// run-flush gather. Thread tid owns exactly dlow==tid (16 consecutive keys).
// perm entry = rl<<17 | src (21 bits).
// ---------------------------------------------------------------------------
__global__ __launch_bounds__(256) void fine_sort(const int* __restrict__ entries,
                                                 const int* __restrict__ histS,
                                                 int* __restrict__ perm,
                                                 int* __restrict__ off,
                                                 int nbuck) {
    __shared__ int cnt[4096];
    __shared__ int bs[256];
    const int tid = threadIdx.x, b = blockIdx.x;
    const int start = histS[b * NB];
    const int end   = (b + 1 < nbuck) ? histS[(b + 1) * NB] : N_EDGES;

#pragma unroll
    for (int k = 0; k < 16; ++k) cnt[tid * 16 + k] = 0;
    __syncthreads();
    for (int i = start + tid; i < end; i += 256)
        atomicAdd(&cnt[entries[i] >> 17], 1);
    __syncthreads();

    int c[16];
    int tsum = 0;
#pragma unroll
    for (int k = 0; k < 16; ++k) { c[k] = cnt[tid * 16 + k]; tsum += c[k]; }
    bs[tid] = tsum;
    __syncthreads();
    for (int st = 1; st < 256; st <<= 1) {
        int t = (tid >= st) ? bs[tid - st] : 0;
        __syncthreads();
        bs[tid] += t;
        __syncthreads();
    }
    const int excl = bs[tid] - tsum;   // exclusive prefix of this dlow group

    const int d = b * 256 + tid;
    if (d < N_NODES) off[d] = start + excl;
    if (b == nbuck - 1 && tid == 0) off[N_NODES] = N_EDGES;

    int run = excl;
#pragma unroll
    for (int k = 0; k < 16; ++k) { cnt[tid * 16 + k] = run; run += c[k]; }
    __syncthreads();
    for (int i = start + tid; i < end; i += 256) {
        int en = entries[i];
        int p = atomicAdd(&cnt[en >> 17], 1);
        perm[start + p] = en & 0x1FFFFF;   // rl<<17 | src
    }
}

// ---------------------------------------------------------------------------
// FUSED gather + GEMM: one 512-thread block covers 16 nodes.
// Phase A: each of 8 waves runs the rel-run gather (round-7 form) for 2
//   nodes, writing z rows (bf16) into a padded LDS tile [16][ZROW] instead of
//   global zb. This deletes the 205 MB zb buffer and its ~405 MB HBM
//   round-trip (round-9 lesson: global zb always pays HBM).
// Phase B: out(16x128) = z(16x1024) * Ut^T(128x1024) + bias. Each wave owns
//   one 16-col tile: 32 x mfma_16x16x32_bf16; A-frag from LDS (row pad ->
//   2-way banks, free), B-frag streamed from L2-resident Ut (256 KB).
// ---------------------------------------------------------------------------
__global__ __launch_bounds__(512) void fused_gz(const int* __restrict__ off,
                                                const int* __restrict__ perm,
                                                const unsigned short* __restrict__ xb,
                                                const float* __restrict__ w_comp,
                                                const unsigned short* __restrict__ Ut,
                                                const float* __restrict__ bias,
                                                float* __restrict__ out) {
    __shared__ unsigned short zt[16 * ZROW];   // 33 KB
    __shared__ float csh[NUM_RELS * NUM_BASES];
    if (threadIdx.x < NUM_RELS * NUM_BASES) csh[threadIdx.x] = w_comp[threadIdx.x];
    __syncthreads();

    const int wid  = threadIdx.x >> 6;
    const int lane = threadIdx.x & 63;
    const int nbase = blockIdx.x * 16;

    // ---- Phase A: gather 2 nodes per wave into LDS z tile ----
    for (int i = 0; i < 2; ++i) {
        const int lr = wid * 2 + i;            // local row 0..15
        const int d  = nbase + lr;
        float2 z[8];
#pragma unroll
        for (int b = 0; b < 8; ++b) z[b] = make_float2(0.f, 0.f);

        if (d < N_NODES) {
            const int e0 = off[d], e1 = off[d + 1];
            const unsigned short* xl = xb + lane * 2;
            int cur = -1;
            float2 srun = make_float2(0.f, 0.f);

            auto flush = [&]() {
                const float4 cA = *reinterpret_cast<const float4*>(&csh[cur * 8]);
                const float4 cB = *reinterpret_cast<const float4*>(&csh[cur * 8 + 4]);
                z[0].x += cA.x * srun.x; z[0].y += cA.x * srun.y;
                z[1].x += cA.y * srun.x; z[1].y += cA.y * srun.y;
                z[2].x += cA.z * srun.x; z[2].y += cA.z * srun.y;
                z[3].x += cA.w * srun.x; z[3].y += cA.w * srun.y;
                z[4].x += cB.x * srun.x; z[4].y += cB.x * srun.y;
                z[5].x += cB.y * srun.x; z[5].y += cB.y * srun.y;
                z[6].x += cB.z * srun.x; z[6].y += cB.z * srun.y;
                z[7].x += cB.w * srun.x; z[7].y += cB.w * srun.y;
            };
            auto step = [&](int p, ushort2 v) {
                int rl = p >> 17;
                if (rl != cur) {               // wave-uniform branch
                    flush();
                    cur = rl;
                    srun = make_float2(0.f, 0.f);
                }
                srun.x += bf2f(v.x);
                srun.y += bf2f(v.y);
            };

            if (e0 < e1) {
                cur = perm[e0] >> 17;
                int e = e0;
                for (; e + 8 <= e1; e += 8) {
                    int p[8];
#pragma unroll
                    for (int j = 0; j < 8; ++j) p[j] = perm[e + j];
                    ushort2 v[8];
#pragma unroll
                    for (int j = 0; j < 8; ++j)
                        v[j] = *reinterpret_cast<const ushort2*>(
                            xl + (size_t)(p[j] & 0x1FFFF) * 128);
#pragma unroll
                    for (int j = 0; j < 8; ++j) step(p[j], v[j]);
                }
                for (; e < e1; ++e) {
                    int p = perm[e];
                    ushort2 v = *reinterpret_cast<const ushort2*>(
                        xl + (size_t)(p & 0x1FFFF) * 128);
                    step(p, v);
                }
                flush();
            }
        }

        // write z row to LDS (bf16). byte addr = lr*2064 + b*256 + lane*4.
        unsigned short* zr = &zt[lr * ZROW + lane * 2];
#pragma unroll
        for (int b = 0; b < 8; ++b) {
            unsigned int u = (unsigned int)f2bf_rne(z[b].x)
                           | ((unsigned int)f2bf_rne(z[b].y) << 16);
            *reinterpret_cast<unsigned int*>(zr + b * 128) = u;
        }
    }
    __syncthreads();

    // ---- Phase B: out(16x128) = z * Ut^T, one 16-col tile per wave ----
    const int ml = lane & 15, kg = lane >> 4;
    const int col0 = wid * 16;
    v4f acc = (v4f){0.f, 0.f, 0.f, 0.f};
    const unsigned short* gB = Ut + (size_t)(col0 + ml) * 1024 + kg * 8;
#pragma unroll 4
    for (int kt = 0; kt < 32; ++kt) {
        short8 af = *reinterpret_cast<const short8*>(&zt[ml * ZROW + kt * 32 + kg * 8]);
        short8 bf = *reinterpret_cast<const short8*>(gB + kt * 32);
        acc = __builtin_amdgcn_mfma_f32_16x16x32_bf16(af, bf, acc, 0, 0, 0);
    }

    const float bv = bias[col0 + ml];
#pragma unroll
    for (int rr = 0; rr < 4; ++rr) {
        int row = nbase + kg * 4 + rr;
        if (row < N_NODES)
            out[(size_t)row * OUT_FEAT + col0 + ml] = acc[rr] + bv;
    }
}

static inline size_t align256(size_t a) { return (a + 255) & ~(size_t)255; }

extern "C" void kernel_launch(void* const* d_in, const int* in_sizes, int n_in,
                              void* d_out, int out_size, void* d_ws, size_t ws_size,
                              hipStream_t stream) {
    const float* x      = (const float*)d_in[0];
    const float* weight = (const float*)d_in[1];
    const float* w_comp = (const float*)d_in[2];
    const float* h_bias = (const float*)d_in[3];
    const int*   src    = (const int*)d_in[4];
    const int*   dst    = (const int*)d_in[5];
    const int*   etypes = (const int*)d_in[6];
    float* out = (float*)d_out;

    const int nbuck = NBKT;
    const int K2 = nbuck * NB;                 // 200192
    const int G2 = (K2 + 4095) / 4096;         // 49

    // Workspace layout (~53 MB): Ut | xb | perm | off | partial | entries | histG
    size_t a = 512 * 1024;                                    // Ut
    size_t xb_o = a;   a = align256(a + (size_t)M_PAD * 128 * 2);
    size_t perm_o = a; a = align256(a + (size_t)N_EDGES * 4);
    size_t off_o = a;  a = align256(a + ((size_t)N_NODES + 1) * 4);
    size_t part_o = a; a = align256(a + 512 * 4);
    size_t ent_o = a;  a = align256(a + (size_t)N_EDGES * 4);
    size_t hist_o = a; a = align256(a + (size_t)K2 * 4);

    char* w = (char*)d_ws;
    unsigned short* Ut      = (unsigned short*)(w);
    unsigned short* xb      = (unsigned short*)(w + xb_o);
    int*            perm    = (int*)(w + perm_o);
    int*            off     = (int*)(w + off_o);
    int*            partial = (int*)(w + part_o);
    int*            entries = (int*)(w + ent_o);
    int*            histG   = (int*)(w + hist_o);

    conv_x<<<12512, 256, 0, stream>>>(x, xb);
    build_ut<<<512, 256, 0, stream>>>(weight, Ut);

    coarse_hist<<<NB, 512, nbuck * 4, stream>>>(dst, histG, nbuck);
    scan_part<<<G2, 256, 0, stream>>>(histG, partial, K2);
    scan_mid<<<1, 512, 0, stream>>>(partial, G2);
    scan_final<<<G2, 256, 0, stream>>>(histG, partial, K2);
    coarse_place<<<NB, 512, nbuck * 4, stream>>>(src, dst, etypes, histG, entries, nbuck);
    fine_sort<<<nbuck, 256, 0, stream>>>(entries, histG, perm, off, nbuck);

    fused_gz<<<M_PAD / 16, 512, 0, stream>>>(off, perm, xb, w_comp, Ut, h_bias, out);
}

// Round 12
// 406.457 us; speedup vs baseline: 1.2166x; 1.2166x over previous
//
#include <hip/hip_runtime.h>
#include <hip/hip_bf16.h>
#include <stdint.h>

#define N_NODES   100000
#define N_EDGES   3200000
#define IN_FEAT   128
#define OUT_FEAT  128
#define NUM_RELS  16
#define NUM_BASES 8
#define M_PAD     100096      // 782 * 128
#define NBKT      391         // coarse buckets = ceil(100000/256)
#define NB        512         // blocks in coarse hist/place (must match both)

using short8 = __attribute__((ext_vector_type(8))) short;
using v4f    = __attribute__((ext_vector_type(4))) float;

__device__ inline unsigned short f2bf_rne(float f) {
    __hip_bfloat16 h = __float2bfloat16(f);
    return *reinterpret_cast<unsigned short*>(&h);
}
__device__ inline float bf2f(unsigned short u) {
    union { uint32_t i; float f; } x;
    x.i = ((uint32_t)u) << 16;
    return x.f;
}

// ---------------------------------------------------------------------------
// Fused preprocessing: disjoint block ranges do
//   [0, 6256)        : x fp32 -> bf16 (pad to M_PAD rows)     -- BW-bound
//   [6256, 6768)     : dst histogram into histG               -- latency-bound
//   [6768, 7024)     : Ut[o][b*128+i] = bf16(weight[b][i][o]) -- tiny
// The latency-bound hist runs concurrently with the streaming conv, so the
// dispatch costs ~max(conv, hist) instead of their sum (round-11 analysis:
// these three were ~41 us serial).
// ---------------------------------------------------------------------------
__global__ __launch_bounds__(512) void fused_pre(const float* __restrict__ x,
                                                 unsigned short* __restrict__ xb,
                                                 const int* __restrict__ dst,
                                                 int* __restrict__ histG,
                                                 const float* __restrict__ weight,
                                                 unsigned short* __restrict__ Ut,
                                                 int nbuck) {
    const int b = blockIdx.x;
    if (b < 6256) {                       // conv_x: 6256*512 = M_PAD*128/4 ids
        int id = b * 512 + threadIdx.x;
        int base = id * 4;
        ushort4 o;
        if (base < N_NODES * IN_FEAT) {
            const float4 v = reinterpret_cast<const float4*>(x)[id];
            o.x = f2bf_rne(v.x); o.y = f2bf_rne(v.y);
            o.z = f2bf_rne(v.z); o.w = f2bf_rne(v.w);
        } else {
            o.x = o.y = o.z = o.w = 0;
        }
        reinterpret_cast<ushort4*>(xb)[id] = o;
    } else if (b < 6256 + NB) {           // coarse_hist
        extern __shared__ int lh[];
        const int hb = b - 6256;
        for (int i = threadIdx.x; i < nbuck; i += 512) lh[i] = 0;
        __syncthreads();
        const int NG = N_EDGES / 4;
        const int stride = NB * 512;
        for (int g = hb * 512 + threadIdx.x; g < NG; g += stride) {
            const int4 d4 = reinterpret_cast<const int4*>(dst)[g];
            atomicAdd(&lh[d4.x >> 8], 1);
            atomicAdd(&lh[d4.y >> 8], 1);
            atomicAdd(&lh[d4.z >> 8], 1);
            atomicAdd(&lh[d4.w >> 8], 1);
        }
        __syncthreads();
        for (int i = threadIdx.x; i < nbuck; i += 512)
            histG[i * NB + hb] = lh[i];
    } else {                              // build_ut: 256*512 = 131072 ids
        int id = (b - 6256 - NB) * 512 + threadIdx.x;
        int o  = id >> 10;
        int kk = id & 1023;
        int bb = kk >> 7;
        int i  = kk & 127;
        Ut[id] = f2bf_rne(weight[(bb * IN_FEAT + i) * OUT_FEAT + o]);
    }
}

// ---------------------------------------------------------------------------
// 2-level in-place exclusive scan of data[0..K): part -> mid -> final
// ---------------------------------------------------------------------------
__global__ void scan_part(const int* __restrict__ data, int* __restrict__ partial, int K) {
    __shared__ int sh[256];
    const int tid = threadIdx.x, b = blockIdx.x;
    const int i0 = b * 4096 + tid * 16;
    int s = 0;
#pragma unroll
    for (int k = 0; k < 16; ++k) { int i = i0 + k; if (i < K) s += data[i]; }
    sh[tid] = s;
    __syncthreads();
    for (int st = 128; st > 0; st >>= 1) {
        if (tid < st) sh[tid] += sh[tid + st];
        __syncthreads();
    }
    if (tid == 0) partial[b] = sh[0];
}

__global__ __launch_bounds__(512) void scan_mid(int* __restrict__ partial, int G) {
    __shared__ int sh[512];
    const int tid = threadIdx.x;
    int v = (tid < G) ? partial[tid] : 0;
    sh[tid] = v;
    __syncthreads();
    for (int st = 1; st < 512; st <<= 1) {
        int t = (tid >= st) ? sh[tid - st] : 0;
        __syncthreads();
        sh[tid] += t;
        __syncthreads();
    }
    if (tid < G) partial[tid] = sh[tid] - v;        // exclusive
}

// in-place: each element read before overwrite by the same thread
__global__ void scan_final(int* __restrict__ data, const int* __restrict__ partial, int K) {
    __shared__ int sh[256];
    const int tid = threadIdx.x, b = blockIdx.x;
    const int i0 = b * 4096 + tid * 16;
    int s = 0;
#pragma unroll
    for (int k = 0; k < 16; ++k) { int i = i0 + k; if (i < K) s += data[i]; }
    sh[tid] = s;
    __syncthreads();
    for (int st = 1; st < 256; st <<= 1) {
        int t = (tid >= st) ? sh[tid - st] : 0;
        __syncthreads();
        sh[tid] += t;
        __syncthreads();
    }
    int run = partial[b] + sh[tid] - s;
#pragma unroll
    for (int k = 0; k < 16; ++k) {
        int i = i0 + k;
        if (i < K) {
            int c = data[i];
            data[i] = run;
            run += c;
        }
    }
}

// ---------------------------------------------------------------------------
// Phase 2: place edges into bucket-contiguous regions using exact reserved
// ranges (histS = scanned histG). LDS cursors only.
// entry = (dst&255)<<21 | rl<<17 | src   (29 bits; src < 2^17)
// ---------------------------------------------------------------------------
__global__ __launch_bounds__(512) void coarse_place(const int* __restrict__ src,
                                                    const int* __restrict__ dst,
                                                    const int* __restrict__ et,
                                                    const int* __restrict__ histS,
                                                    int* __restrict__ entries,
                                                    int nbuck) {
    extern __shared__ int cur[];
    for (int i = threadIdx.x; i < nbuck; i += 512)
        cur[i] = histS[i * NB + blockIdx.x];
    __syncthreads();
    const int NG = N_EDGES / 4;
    const int stride = NB * 512;
    for (int g = blockIdx.x * 512 + threadIdx.x; g < NG; g += stride) {
        const int4 s4 = reinterpret_cast<const int4*>(src)[g];
        const int4 d4 = reinterpret_cast<const int4*>(dst)[g];
        const int4 t4 = reinterpret_cast<const int4*>(et)[g];
        int p0 = atomicAdd(&cur[d4.x >> 8], 1);
        int p1 = atomicAdd(&cur[d4.y >> 8], 1);
        int p2 = atomicAdd(&cur[d4.z >> 8], 1);
        int p3 = atomicAdd(&cur[d4.w >> 8], 1);
        entries[p0] = ((d4.x & 255) << 21) | ((t4.x & 15) << 17) | s4.x;
        entries[p1] = ((d4.y & 255) << 21) | ((t4.y & 15) << 17) | s4.y;
        entries[p2] = ((d4.z & 255) << 21) | ((t4.z & 15) << 17) | s4.z;
        entries[p3] = ((d4.w & 255) << 21) | ((t4.w & 15) << 17) | s4.w;
    }
}

// ---------------------------------------------------------------------------
// Phase 3: one block per bucket; counting sort by 12-bit key (dlow<<4 | rl)
// in LDS (2-pass), 512 threads (391 blocks is latency-bound at 1.5/CU; the
// two counting passes halve). Scan portion runs on tid<256 (one dlow each).
// perm entry = src<<8 | rl  (so gather's row byte-offset is a single AND).
// ---------------------------------------------------------------------------
__global__ __launch_bounds__(512) void fine_sort(const int* __restrict__ entries,
                                                 const int* __restrict__ histS,
                                                 int* __restrict__ perm,
                                                 int* __restrict__ off,
                                                 int nbuck) {
    __shared__ int cnt[4096];
    __shared__ int bs[256];
    const int tid = threadIdx.x, b = blockIdx.x;
    const int start = histS[b * NB];
    const int end   = (b + 1 < nbuck) ? histS[(b + 1) * NB] : N_EDGES;

    for (int i = tid; i < 4096; i += 512) cnt[i] = 0;
    __syncthreads();
    for (int i = start + tid; i < end; i += 512)
        atomicAdd(&cnt[entries[i] >> 17], 1);
    __syncthreads();

    int c[16];
    int tsum = 0;
    if (tid < 256) {
#pragma unroll
        for (int k = 0; k < 16; ++k) { c[k] = cnt[tid * 16 + k]; tsum += c[k]; }
        bs[tid] = tsum;
    }
    __syncthreads();
    for (int st = 1; st < 256; st <<= 1) {
        int t = 0;
        if (tid < 256 && tid >= st) t = bs[tid - st];
        __syncthreads();
        if (tid < 256) bs[tid] += t;
        __syncthreads();
    }
    if (tid < 256) {
        const int excl = bs[tid] - tsum;   // exclusive prefix of this dlow group
        const int d = b * 256 + tid;
        if (d < N_NODES) off[d] = start + excl;
        int run = excl;
#pragma unroll
        for (int k = 0; k < 16; ++k) { cnt[tid * 16 + k] = run; run += c[k]; }
    }
    if (b == nbuck - 1 && tid == 0) off[N_NODES] = N_EDGES;
    __syncthreads();
    for (int i = start + tid; i < end; i += 512) {
        int en = entries[i];
        int p = atomicAdd(&cnt[en >> 17], 1);
        perm[start + p] = ((en & 0x1FFFF) << 8) | ((en >> 17) & 15);   // src<<8 | rl
    }
}

// ---------------------------------------------------------------------------
// Basis-space aggregation with rel-run grouping (round-7 form, best measured:
// 144 us). perm = src<<8 | rl: row byte offset = p & 0x01FFFF00 (one v_and),
// rl = p & 15. FETCH ~360 MB is intrinsic xb L2-miss traffic served by L3
// (round-11: unchanged even with zero global z writes) -- not addressable.
// ---------------------------------------------------------------------------
__global__ void gather_z(const int* __restrict__ off, const int* __restrict__ perm,
                         const unsigned short* __restrict__ xb,
                         const float* __restrict__ w_comp,
                         unsigned short* __restrict__ zb) {
    __shared__ float csh[NUM_RELS * NUM_BASES];
    if (threadIdx.x < NUM_RELS * NUM_BASES) csh[threadIdx.x] = w_comp[threadIdx.x];
    __syncthreads();
    const int d = blockIdx.x * 4 + (threadIdx.x >> 6);
    const int lane = threadIdx.x & 63;
    float2 z[8];
#pragma unroll
    for (int b = 0; b < 8; ++b) z[b] = make_float2(0.f, 0.f);

    if (d < N_NODES) {
        const int e0 = off[d], e1 = off[d + 1];
        const char* xB = (const char*)xb + lane * 4;
        int cur = -1;
        float2 srun = make_float2(0.f, 0.f);

        auto flush = [&]() {
            const float4 cA = *reinterpret_cast<const float4*>(&csh[cur * 8]);
            const float4 cB = *reinterpret_cast<const float4*>(&csh[cur * 8 + 4]);
            z[0].x += cA.x * srun.x; z[0].y += cA.x * srun.y;
            z[1].x += cA.y * srun.x; z[1].y += cA.y * srun.y;
            z[2].x += cA.z * srun.x; z[2].y += cA.z * srun.y;
            z[3].x += cA.w * srun.x; z[3].y += cA.w * srun.y;
            z[4].x += cB.x * srun.x; z[4].y += cB.x * srun.y;
            z[5].x += cB.y * srun.x; z[5].y += cB.y * srun.y;
            z[6].x += cB.z * srun.x; z[6].y += cB.z * srun.y;
            z[7].x += cB.w * srun.x; z[7].y += cB.w * srun.y;
        };
        auto step = [&](int p, ushort2 v) {
            int rl = p & 15;
            if (rl != cur) {               // wave-uniform (all lanes same p)
                flush();
                cur = rl;
                srun = make_float2(0.f, 0.f);
            }
            srun.x += bf2f(v.x);
            srun.y += bf2f(v.y);
        };

        if (e0 < e1) {
            cur = perm[e0] & 15;           // first run: no leading flush
            int e = e0;
            for (; e + 8 <= e1; e += 8) {
                int p[8];
#pragma unroll
                for (int j = 0; j < 8; ++j) p[j] = perm[e + j];
                ushort2 v[8];
#pragma unroll
                for (int j = 0; j < 8; ++j)
                    v[j] = *reinterpret_cast<const ushort2*>(
                        xB + (uint32_t)(p[j] & 0x01FFFF00));
#pragma unroll
                for (int j = 0; j < 8; ++j) step(p[j], v[j]);
            }
            for (; e < e1; ++e) {
                int p = perm[e];
                ushort2 v = *reinterpret_cast<const ushort2*>(
                    xB + (uint32_t)(p & 0x01FFFF00));
                step(p, v);
            }
            flush();                       // final run
        }
    }

    // store z row (pad rows d in [N_NODES, M_PAD) get zeros so zgemm reads clean)
    unsigned short* zr = zb + (size_t)d * 1024 + lane * 2;
#pragma unroll
    for (int b = 0; b < 8; ++b) {
        unsigned int u = (unsigned int)f2bf_rne(z[b].x)
                       | ((unsigned int)f2bf_rne(z[b].y) << 16);
        *reinterpret_cast<unsigned int*>(zr + b * 128) = u;
    }
}

// ---------------------------------------------------------------------------
// out = z (M_PAD x 1024) * Ut^T (128 x 1024) + bias.  m97-style 128x128 tile
// with 8-step K-loop via global_load_lds(16B), XOR-swizzled LDS.
// ---------------------------------------------------------------------------
__global__ __launch_bounds__(256, 2) void zgemm(const unsigned short* __restrict__ zb,
                                                const unsigned short* __restrict__ Ut,
                                                const float* __restrict__ bias,
                                                float* __restrict__ out) {
    __shared__ unsigned short lA[128 * 128];
    __shared__ unsigned short lB[128 * 128];

    const int mb = blockIdx.x;
    const int tid  = threadIdx.x;
    const int wid  = tid >> 6;
    const int lane = tid & 63;
    const int wm = wid >> 1, wn = wid & 1;
    const int ml = lane & 15, kgrp = lane >> 4;

    const unsigned short* gA = zb + (size_t)mb * 128 * 1024;

    v4f acc[4][4];
#pragma unroll
    for (int i = 0; i < 4; ++i)
#pragma unroll
        for (int j = 0; j < 4; ++j)
            acc[i][j] = (v4f){0.f, 0.f, 0.f, 0.f};

    for (int kt = 0; kt < 8; ++kt) {
#pragma unroll
        for (int it = 0; it < 8; ++it) {
            int sbase = it * 256 + wid * 64;
            int s = sbase + lane;
            int row = s >> 4;
            int cc = (s & 15) ^ (row & 15);
            __builtin_amdgcn_global_load_lds(
                (const __attribute__((address_space(1))) void*)(gA + (size_t)row * 1024 + kt * 128 + cc * 8),
                (__attribute__((address_space(3))) void*)(&lA[sbase * 8]), 16, 0, 0);
            __builtin_amdgcn_global_load_lds(
                (const __attribute__((address_space(1))) void*)(Ut + (size_t)row * 1024 + kt * 128 + cc * 8),
                (__attribute__((address_space(3))) void*)(&lB[sbase * 8]), 16, 0, 0);
        }
        __syncthreads();

#pragma unroll
        for (int kb = 0; kb < 4; ++kb) {
            const int cc = kb * 4 + kgrp;
            short8 af[4], bfr[4];
#pragma unroll
            for (int tm = 0; tm < 4; ++tm) {
                int rA = wm * 64 + tm * 16 + ml;
                af[tm] = *reinterpret_cast<const short8*>(&lA[(rA * 16 + (cc ^ (rA & 15))) * 8]);
            }
#pragma unroll
            for (int tn = 0; tn < 4; ++tn) {
                int rB = wn * 64 + tn * 16 + ml;
                bfr[tn] = *reinterpret_cast<const short8*>(&lB[(rB * 16 + (cc ^ (rB & 15))) * 8]);
            }
#pragma unroll
            for (int tm = 0; tm < 4; ++tm)
#pragma unroll
                for (int tn = 0; tn < 4; ++tn)
                    acc[tm][tn] = __builtin_amdgcn_mfma_f32_16x16x32_bf16(af[tm], bfr[tn], acc[tm][tn], 0, 0, 0);
        }
        __syncthreads();
    }

    const int row0 = mb * 128 + wm * 64;
    const int col0 = wn * 64;
#pragma unroll
    for (int tm = 0; tm < 4; ++tm)
#pragma unroll
        for (int rr = 0; rr < 4; ++rr) {
            int row = row0 + tm * 16 + kgrp * 4 + rr;
            if (row < N_NODES) {
                size_t rb = (size_t)row * OUT_FEAT;
#pragma unroll
                for (int tn = 0; tn < 4; ++tn) {
                    int col = col0 + tn * 16 + ml;
                    out[rb + col] = acc[tm][tn][rr] + bias[col];
                }
            }
        }
}

static inline size_t align256(size_t a) { return (a + 255) & ~(size_t)255; }

extern "C" void kernel_launch(void* const* d_in, const int* in_sizes, int n_in,
                              void* d_out, int out_size, void* d_ws, size_t ws_size,
                              hipStream_t stream) {
    const float* x      = (const float*)d_in[0];
    const float* weight = (const float*)d_in[1];
    const float* w_comp = (const float*)d_in[2];
    const float* h_bias = (const float*)d_in[3];
    const int*   src    = (const int*)d_in[4];
    const int*   dst    = (const int*)d_in[5];
    const int*   etypes = (const int*)d_in[6];
    float* out = (float*)d_out;

    const int nbuck = NBKT;
    const int K2 = nbuck * NB;                 // 200192
    const int G2 = (K2 + 4095) / 4096;         // 49

    // Workspace layout (total ~244 MB):
    //   Ut 512KB | xb 25.6MB | perm 12.8MB | off 0.4MB | partial | zb 205MB
    // entries (12.8MB) and histG (0.8MB) alias zb -- dead before gather_z.
    size_t a = 512 * 1024;                                    // Ut
    size_t xb_o = a;   a = align256(a + (size_t)M_PAD * 128 * 2);
    size_t perm_o = a; a = align256(a + (size_t)N_EDGES * 4);
    size_t off_o = a;  a = align256(a + ((size_t)N_NODES + 1) * 4);
    size_t part_o = a; a = align256(a + 512 * 4);
    size_t zb_o = a;   // zb: M_PAD * 1024 * 2 = 205 MB

    char* w = (char*)d_ws;
    unsigned short* Ut      = (unsigned short*)(w);
    unsigned short* xb      = (unsigned short*)(w + xb_o);
    int*            perm    = (int*)(w + perm_o);
    int*            off     = (int*)(w + off_o);
    int*            partial = (int*)(w + part_o);
    unsigned short* zb      = (unsigned short*)(w + zb_o);
    int*            entries = (int*)(w + zb_o);                    // alias zb
    int*            histG   = (int*)(w + zb_o + 13 * 1024 * 1024); // alias zb+13MB

    fused_pre<<<6256 + NB + 256, 512, nbuck * 4, stream>>>(x, xb, dst, histG,
                                                           weight, Ut, nbuck);
    scan_part<<<G2, 256, 0, stream>>>(histG, partial, K2);
    scan_mid<<<1, 512, 0, stream>>>(partial, G2);
    scan_final<<<G2, 256, 0, stream>>>(histG, partial, K2);
    coarse_place<<<NB, 512, nbuck * 4, stream>>>(src, dst, etypes, histG, entries, nbuck);
    fine_sort<<<nbuck, 512, 0, stream>>>(entries, histG, perm, off, nbuck);

    gather_z<<<25024, 256, 0, stream>>>(off, perm, xb, w_comp, zb);
    zgemm<<<782, 256, 0, stream>>>(zb, Ut, h_bias, out);
}